// Round 5
// baseline (359.548 us; speedup 1.0000x reference)
//
#include <hip/hip_runtime.h>

#define LOG2_T 14
#define NKEYS  88
#define NB     16
#define DMAX   64   // static bound on distinct key_bins runs (actual ~57)
#define TOPK   14   // #elements >= v[74] among 88
#define CHUNK  16   // d's per register-staged load chunk (48 loads in flight)

// Exact semantics (validated absmax=0 in rounds 2 and 4):
//   E_d = ((expf(x0) * sel(expf(x1))) * sel(expf(x2)))  — reference f32 order
//   probs = (E >= v74); v74 = weighted 14th-largest distinct value
//   (thresh = lerp(v73,v74,0.95) always lies in (v73, v74] -> same predicate)
__global__ __launch_bounds__(256, 4) void tsp_kernel(
    const float* __restrict__ mel,
    const int*   __restrict__ key_bins,
    float*       __restrict__ out)
{
    __shared__ int s_bin[DMAX];
    __shared__ int s_mult[DMAX];
    __shared__ int s_start[DMAX];
    __shared__ int s_wcnt[4];

    const int tid  = threadIdx.x;
    const int lane = tid & 63;
    const int wid  = tid >> 6;

    // ---- Run table, lane-parallel (no serial thread-0 scan) ----
    bool nf = false; int mybin = 0;
    if (tid < NKEYS) {
        mybin = key_bins[tid];
        const int prev = tid ? key_bins[tid - 1] : -1;
        nf = (mybin != prev);
    }
    const unsigned long long bm = __ballot(nf);
    const int pre = __popcll(bm & ((1ull << lane) - 1ull));
    if (lane == 0) s_wcnt[wid] = __popcll(bm);
    __syncthreads();
    if (nf) {
        int r = pre;
        for (int w = 0; w < wid; ++w) r += s_wcnt[w];
        s_start[r] = tid;
        s_bin[r]   = mybin;
    }
    const int D = s_wcnt[0] + s_wcnt[1];   // keys live in waves 0-1 only
    __syncthreads();
    if (tid < DMAX) {
        if (tid < D) {
            const int nxt = (tid == D - 1) ? NKEYS : s_start[tid + 1];
            s_mult[tid] = nxt - s_start[tid];
        } else {
            s_bin[tid] = 0; s_mult[tid] = 0; s_start[tid] = NKEYS;
        }
    }
    __syncthreads();

    const int bidx = blockIdx.x;             // 1024 = 16 batches x 64 tiles
    const int b    = bidx >> 6;
    const int t    = ((bidx & 63) << 8) + tid;
    const float* melb = mel + ((size_t)b << 21);   // b * 128 * 16384

    // ---- Phase 1: distinct energies; chunked register-staged loads ----
    float e[DMAX];
    #pragma unroll
    for (int c = 0; c < DMAX; c += CHUNK) {
        float x0[CHUNK], x1[CHUNK], x2[CHUNK];
        int   bns[CHUNK];
        #pragma unroll
        for (int i = 0; i < CHUNK; ++i) {      // issue 48 independent loads
            const int d  = c + i;
            const int bn = __builtin_amdgcn_readfirstlane(s_bin[d]);
            const int b1 = (2 * bn < 128) ? 2 * bn : 127;
            const int b2 = (3 * bn < 128) ? 3 * bn : 127;
            bns[i] = bn;
            x0[i] = melb[((size_t)bn << LOG2_T) + t];
            x1[i] = melb[((size_t)b1 << LOG2_T) + t];
            x2[i] = melb[((size_t)b2 << LOG2_T) + t];
        }
        #pragma unroll
        for (int i = 0; i < CHUNK; ++i) {      // consume
            const int d  = c + i;
            const int bn = bns[i];
            float v = expf(x0[i]);
            v *= (bn < 64) ? expf(x1[i]) : 1.0f;   // harmonic 2: L = 64
            v *= (bn < 43) ? expf(x2[i]) : 1.0f;   // harmonic 3: L = 43
            e[d] = (d < D) ? v : 0.0f;             // pads: value 0, weight 0
        }
    }

    // ---- Phase A: top-14 distinct values via masked ternary-tree max ----
    float tv[TOPK];
    float cur = __builtin_inff();
    #pragma unroll
    for (int i = 0; i < TOPK; ++i) {
        float t1[22];
        #pragma unroll
        for (int j = 0; j < 21; ++j) {
            const float a0 = (e[3*j+0] < cur) ? e[3*j+0] : -1.0f;
            const float a1 = (e[3*j+1] < cur) ? e[3*j+1] : -1.0f;
            const float a2 = (e[3*j+2] < cur) ? e[3*j+2] : -1.0f;
            t1[j] = fmaxf(fmaxf(a0, a1), a2);      // -> v_max3_f32
        }
        t1[21] = (e[63] < cur) ? e[63] : -1.0f;
        float t2[8];
        #pragma unroll
        for (int j = 0; j < 7; ++j)
            t2[j] = fmaxf(fmaxf(t1[3*j], t1[3*j+1]), t1[3*j+2]);
        t2[7] = t1[21];
        const float t3a = fmaxf(fmaxf(t2[0], t2[1]), t2[2]);
        const float t3b = fmaxf(fmaxf(t2[3], t2[4]), t2[5]);
        const float t3c = fmaxf(t2[6], t2[7]);
        const float mx  = fmaxf(fmaxf(t3a, t3b), t3c);
        tv[i] = mx;
        cur   = mx;
    }

    // ---- Phase B: weighted rank of the 14 candidates, one pass over d ----
    int W[TOPK];
    #pragma unroll
    for (int i = 0; i < TOPK; ++i) W[i] = 0;
    #pragma unroll
    for (int d = 0; d < DMAX; ++d) {
        const int   mlt = s_mult[d];              // uniform LDS broadcast
        const float ed  = e[d];
        #pragma unroll
        for (int i = 0; i < TOPK; ++i) W[i] += (ed >= tv[i]) ? mlt : 0;
    }
    float thr = tv[TOPK - 1];                     // W guaranteed >= 14 here
    #pragma unroll
    for (int i = TOPK - 2; i >= 0; --i) thr = (W[i] >= TOPK) ? tv[i] : thr;

    // ---- Output: per-run broadcast (uniform bounds), two tuple copies ----
    float*       out2    = out + ((size_t)(NB * NKEYS) << LOG2_T);
    const size_t colbase = (((size_t)b * NKEYS) << LOG2_T) + t;
    #pragma unroll
    for (int d = 0; d < DMAX; ++d) {
        const int ks = __builtin_amdgcn_readfirstlane(s_start[d]);
        const int ke = ks + __builtin_amdgcn_readfirstlane(s_mult[d]);
        const float p = (e[d] >= thr) ? 1.0f : 0.0f;
        for (int k = ks; k < ke; ++k) {           // empty for pads
            const size_t idx = colbase + ((size_t)k << LOG2_T);
            out[idx]  = p;
            out2[idx] = p;
        }
    }
}

extern "C" void kernel_launch(void* const* d_in, const int* in_sizes, int n_in,
                              void* d_out, int out_size, void* d_ws, size_t ws_size,
                              hipStream_t stream) {
    const float* mel = (const float*)d_in[0];
    const int*   kb  = (const int*)d_in[1];
    float*       out = (float*)d_out;
    tsp_kernel<<<dim3(1024), dim3(256), 0, stream>>>(mel, kb, out);
}